// Round 10
// baseline (513.489 us; speedup 1.0000x reference)
//
#include <hip/hip_runtime.h>

#define LBL 64
#define TT 1024
#define BB 256
#define BOS 62
#define EOS 63
#define NEGV -10000.0f

typedef float v4f __attribute__((ext_vector_type(4)));

__device__ __forceinline__ float rl_f(float v, int l) {
    return __uint_as_float(__builtin_amdgcn_readlane(__float_as_uint(v), l));
}

// ONE WAVE per sentence, ZERO barriers. lane = next-label n.
// fv stays in REGISTERS (readlane broadcast) -> no per-step LDS round-trip.
// Value-only fmax trees give m; argmax recovered exactly by equality chains:
// first 8-group with groupmax==m, then recompute that group's 8 sums from LDS
// (same f32 adds, bitwise-equal) and take first k with sum==m  == np.argmax.
__global__ __launch_bounds__(64, 1) void viterbi_kernel(
    const float* __restrict__ X, const float* __restrict__ trans,
    float* __restrict__ out)
{
    __shared__ __align__(16) float fvrow[LBL];       // fv_{t-1} (gather only)
    __shared__ __align__(16) float tlds[LBL * LBL];  // [p][n] original layout
    __shared__ unsigned char bp[TT][LBL];            // 64 KiB backpointers
    __shared__ unsigned char path_s[TT];

    const int lane = threadIdx.x;            // next-label n
    const int b    = blockIdx.x;

    // tc[p] = T[p][n] in registers (compile-time indexed only)
    float tc[LBL];
#pragma unroll
    for (int p = 0; p < LBL; ++p) tc[p] = trans[p * LBL + lane];
    // LDS copy, original [p][n] layout: gather reads are lane-consecutive
    // (addr = p*256B + 4*lane -> bank = lane%32, conflict-free)
#pragma unroll
    for (int p = 0; p < LBL; ++p) tlds[p * LBL + lane] = tc[p];

    const float* Xb = X + (size_t)b * TT * LBL + lane;

    float eA[4], eB[4];
#pragma unroll
    for (int j = 0; j < 4; ++j) eA[j] = Xb[(size_t)j * LBL];

    float fvv = (lane == BOS) ? 0.0f : NEGV;
    fvrow[lane] = fvv;   // fv_{-1} for step 0's gather (single wave: program order)

    auto STEP = [&](int t, float e) {
        // ---- value phase: m = max_p(fv[p] + T[p][n]), fv via readlane ----
        float vg[8];
#pragma unroll
        for (int g = 0; g < 8; ++g) {
            float s0 = rl_f(fvv, 8*g+0) + tc[8*g+0];
            float s1 = rl_f(fvv, 8*g+1) + tc[8*g+1];
            float s2 = rl_f(fvv, 8*g+2) + tc[8*g+2];
            float s3 = rl_f(fvv, 8*g+3) + tc[8*g+3];
            float s4 = rl_f(fvv, 8*g+4) + tc[8*g+4];
            float s5 = rl_f(fvv, 8*g+5) + tc[8*g+5];
            float s6 = rl_f(fvv, 8*g+6) + tc[8*g+6];
            float s7 = rl_f(fvv, 8*g+7) + tc[8*g+7];
            vg[g] = fmaxf(fmaxf(fmaxf(s0, s1), fmaxf(s2, s3)),
                          fmaxf(fmaxf(s4, s5), fmaxf(s6, s7)));
        }
        const float m = fmaxf(fmaxf(fmaxf(vg[0], vg[1]), fmaxf(vg[2], vg[3])),
                              fmaxf(fmaxf(vg[4], vg[5]), fmaxf(vg[6], vg[7])));

        // ---- index phase (off the fv critical path, feeds bp only) ----
        // first group with vg==m (reverse cndmask chain: lowest g wins)
        int gs = 7;
#pragma unroll
        for (int g = 6; g >= 0; --g) gs = (vg[g] == m) ? g : gs;

        // recompute group gs's 8 sums: bitwise-identical f32 adds
        const v4f fq0 = *(const v4f*)((const char*)fvrow + (gs << 5));
        const v4f fq1 = *(const v4f*)((const char*)fvrow + (gs << 5) + 16);
        const float* tg = (const float*)((const char*)tlds + (gs << 11)) + lane;
        float q0 = fq0.x + tg[0 * LBL];   // ds_read_b32, shared vaddr +
        float q1 = fq0.y + tg[1 * LBL];   //  compile-time offset: immediates
        float q2 = fq0.z + tg[2 * LBL];
        float q3 = fq0.w + tg[3 * LBL];
        float q4 = fq1.x + tg[4 * LBL];
        float q5 = fq1.y + tg[5 * LBL];
        float q6 = fq1.z + tg[6 * LBL];
        float q7 = fq1.w + tg[7 * LBL];
        int k = 7;
        k = (q6 == m) ? 6 : k;
        k = (q5 == m) ? 5 : k;
        k = (q4 == m) ? 4 : k;
        k = (q3 == m) ? 3 : k;
        k = (q2 == m) ? 2 : k;
        k = (q1 == m) ? 1 : k;
        k = (q0 == m) ? 0 : k;            // lowest k wins = first occurrence
        bp[t][lane] = (unsigned char)((gs << 3) | k);

        // ---- advance; publish fv_t for next step's gather ----
        fvv = m + e;                      // exact f32 add == numpy
        fvrow[lane] = fvv;                // after the reads above (program order)
    };

    for (int w8 = 0; w8 < TT / 4; w8 += 2) {
        const int base = w8 * 4;
#pragma unroll
        for (int j = 0; j < 4; ++j) {      // prefetch window +1 (never drained:
            int st = base + 4 + j;         //  no barriers anywhere in the loop)
            if (st > TT - 1) st = TT - 1;
            eB[j] = Xb[(size_t)st * LBL];
        }
#pragma unroll
        for (int j = 0; j < 4; ++j) STEP(base + j, eA[j]);
#pragma unroll
        for (int j = 0; j < 4; ++j) {      // prefetch window +2
            int st = base + 8 + j;
            if (st > TT - 1) st = TT - 1;
            eA[j] = Xb[(size_t)st * LBL];
        }
#pragma unroll
        for (int j = 0; j < 4; ++j) STEP(base + 4 + j, eB[j]);
    }

    // ---- termination + wave argmax (butterfly, lower index wins ties) ----
    float bv = fvv + trans[lane * LBL + EOS];
    int   bi = lane;
#pragma unroll
    for (int d = 1; d < 64; d <<= 1) {
        float ov = __shfl_xor(bv, d, 64);
        int   oi = __shfl_xor(bi, d, 64);
        if (ov > bv || (ov == bv && oi < bi)) { bv = ov; bi = oi; }
    }
    if (lane == 0) out[b] = bv;

    // ---- backtrack: prefetch bp rows, chase via readlane (r5-validated) ----
    int stag = bi;   // wave-uniform
    unsigned char r0 = bp[TT-1][lane];
    unsigned char r1 = bp[TT-2][lane];
    unsigned char r2 = bp[TT-3][lane];
    unsigned char r3 = bp[TT-4][lane];
    for (int t4 = TT - 1; t4 >= 3; t4 -= 4) {
        int q0 = t4-4, q1 = t4-5, q2 = t4-6, q3 = t4-7;
        if (q0 < 0) q0 = 0;  if (q1 < 0) q1 = 0;
        if (q2 < 0) q2 = 0;  if (q3 < 0) q3 = 0;
        unsigned char m0 = bp[q0][lane];
        unsigned char m1 = bp[q1][lane];
        unsigned char m2 = bp[q2][lane];
        unsigned char m3 = bp[q3][lane];
        if (lane == ((t4-0) & 63)) path_s[t4-0] = (unsigned char)stag;
        stag = __builtin_amdgcn_readlane((int)r0, stag);
        if (lane == ((t4-1) & 63)) path_s[t4-1] = (unsigned char)stag;
        stag = __builtin_amdgcn_readlane((int)r1, stag);
        if (lane == ((t4-2) & 63)) path_s[t4-2] = (unsigned char)stag;
        stag = __builtin_amdgcn_readlane((int)r2, stag);
        if (lane == ((t4-3) & 63)) path_s[t4-3] = (unsigned char)stag;
        stag = __builtin_amdgcn_readlane((int)r3, stag);
        r0 = m0; r1 = m1; r2 = m2; r3 = m3;
    }

    // coalesced float path write (single wave, LDS program order)
    float* po = out + BB + (size_t)b * TT;
#pragma unroll
    for (int i = 0; i < TT / LBL; ++i)
        po[i * LBL + lane] = (float)path_s[i * LBL + lane];
}

extern "C" void kernel_launch(void* const* d_in, const int* in_sizes, int n_in,
                              void* d_out, int out_size, void* d_ws, size_t ws_size,
                              hipStream_t stream)
{
    const float* X     = (const float*)d_in[0];   // [256, 1024, 64]
    const float* trans = (const float*)d_in[1];   // [64, 64]
    float* out = (float*)d_out;                   // [256] scores ++ [256*1024] path

    viterbi_kernel<<<dim3(BB), dim3(64), 0, stream>>>(X, trans, out);
}